// Round 10
// baseline (110.254 us; speedup 1.0000x reference)
//
#include <hip/hip_runtime.h>

// MHA: B=2, S=2048, D=1024, H=16, DH=64. f32 in/out, bf16 MFMA internally.
// wconv_kernel: W q/k/v f32 -> bf16 (read 16x by gemm; convert once).
// proj_kernel:  fused Q/K/V = X @ W^T (768 blocks, 128x128, BK=32). ALL staging
//               via global_load_lds (A as f32 -> cvt_pk at fragment read; B bf16).
//               LDS linear dest + involution swizzle on the GLOBAL source and
//               the read side (rule #21). 3-buffer ring, depth-3 prefetch,
//               counted vmcnt (12/6/0), lgkmcnt(0) before overwrite barrier.
// attn_kernel:  paired q-tiles flash attention (unchanged from round 8).

typedef unsigned short u16;
typedef unsigned int u32;
typedef u16 u16x4 __attribute__((ext_vector_type(4)));
typedef u16 u16x8 __attribute__((ext_vector_type(8)));
typedef u32 u32x2 __attribute__((ext_vector_type(2)));
typedef u32 u32x4 __attribute__((ext_vector_type(4)));
typedef __bf16 bf16x8 __attribute__((ext_vector_type(8)));
typedef float f32x4 __attribute__((ext_vector_type(4)));

static __device__ __forceinline__ u16 f2bf(float f) {
  unsigned u = __builtin_bit_cast(unsigned, f);
  return (u16)((u + 0x7FFFu + ((u >> 16) & 1u)) >> 16);
}

static __device__ __forceinline__ u32 cvt_pk_bf16(float lo, float hi) {
  u32 r;
  asm("v_cvt_pk_bf16_f32 %0, %1, %2" : "=v"(r) : "v"(lo), "v"(hi));
  return r;
}

static __device__ __forceinline__ u16x8 cvt8(float4 f0, float4 f1) {
  u32x4 v;
  v[0] = cvt_pk_bf16(f0.x, f0.y);
  v[1] = cvt_pk_bf16(f0.z, f0.w);
  v[2] = cvt_pk_bf16(f1.x, f1.y);
  v[3] = cvt_pk_bf16(f1.z, f1.w);
  return __builtin_bit_cast(u16x8, v);
}

static __device__ __forceinline__ f32x4 mfma16(u16x8 a, u16x8 b, f32x4 c) {
  return __builtin_amdgcn_mfma_f32_16x16x32_bf16(
      __builtin_bit_cast(bf16x8, a), __builtin_bit_cast(bf16x8, b), c, 0, 0, 0);
}

static __device__ __forceinline__ float bperm_f(int lane, float v) {
  return __builtin_bit_cast(
      float, __builtin_amdgcn_ds_bpermute(lane * 4, __builtin_bit_cast(int, v)));
}

// async global->LDS, 16B/lane; LDS dest = wave-uniform base (+ lane*16 by HW)
#define GLOAD16(GSRC, LDST)                                                  \
  __builtin_amdgcn_global_load_lds(                                         \
      (const __attribute__((address_space(1))) unsigned int*)(GSRC),        \
      (__attribute__((address_space(3))) unsigned int*)(LDST), 16, 0, 0)

#define FENCE() asm volatile("" ::: "memory")
#define BARX()                        \
  do {                                \
    __builtin_amdgcn_s_barrier();     \
    FENCE();                          \
  } while (0)

// ---------------------------------------------------------------- W f32->bf16
__global__ __launch_bounds__(256) void wconv_kernel(
    const float* __restrict__ Wq, const float* __restrict__ Wk,
    const float* __restrict__ Wv, u16* __restrict__ dst) {
  const float* src = (blockIdx.y == 0) ? Wq : (blockIdx.y == 1) ? Wk : Wv;
  u16* d = dst + (size_t)blockIdx.y * (1024 * 1024);
  const int i = (blockIdx.x * 256 + threadIdx.x) * 8;
  const float4 f0 = *(const float4*)(src + i);
  const float4 f1 = *(const float4*)(src + i + 4);
  *(u16x8*)(d + i) = cvt8(f0, f1);
}

// ---------------------------------------------------------------- projections
__global__ __launch_bounds__(256) void proj_kernel(
    const float* __restrict__ Xq, const float* __restrict__ Xk, const float* __restrict__ Xv,
    const u16* __restrict__ Wbf,
    u16* __restrict__ Qb, u16* __restrict__ Kb, u16* __restrict__ Vt) {
  // XCD-chunk remap (768 = 8*96, bijective); n fastest within a chunk so the
  // 8 n-blocks sharing an X m-slice run consecutively on one XCD.
  const int d0 = blockIdx.x;
  const int tid = (d0 & 7) * 96 + (d0 >> 3);
  const int nI = tid % 24, mI = tid / 24;
  const int mode = nI >> 3;        // 0=Q 1=K 2=V
  const int m0 = mI * 128;
  const int n0 = (nI & 7) * 128;

  const float* __restrict__ X = (mode == 0) ? Xq : (mode == 1) ? Xk : Xv;
  const u16* __restrict__ W = Wbf + (size_t)mode * (1024 * 1024);

  // A: f32 [128 rows][8 slots of 16B] -> row r at byte r*128, slot swizzled
  //    by s ^= (r&7) on BOTH source and read (involution; LDS itself linear).
  // B: bf16 [128 rows][4 slots of 16B] -> row r at byte r*64, s ^= ((r>>1)&3).
  __shared__ __align__(16) char As[3][128 * 128];
  __shared__ __align__(16) char Bs[3][128 * 64];

  const int t = threadIdx.x;
  const int lane = t & 63;
  const int w = t >> 6;
  const int wm = w >> 1, wn = w & 1;
  const int lr = lane & 15, lg = lane >> 4;

  // A staging: 16 instrs of 1KB (8 rows x 8 slots); 4 per wave.
  // Instr j writes LDS [j*1024, +1024): lane -> row j*8+(lane>>3), phys slot
  // lane&7, which must hold logical k-slot (lane&7)^(row&7) = (lane&7)^(lane>>3).
  const float* aptr[4];
  int aoff[4];
#pragma unroll
  for (int jj = 0; jj < 4; ++jj) {
    const int j = w * 4 + jj;
    aptr[jj] = X + (size_t)(m0 + j * 8 + (lane >> 3)) * 1024 +
               ((lane & 7) ^ (lane >> 3)) * 4;
    aoff[jj] = j * 1024;
  }
  // B staging: 8 instrs of 1KB (16 rows x 4 slots); 2 per wave.
  // Instr j: lane -> row j*16+(lane>>2), phys slot lane&3 holds logical
  // (lane&3)^((row>>1)&3) = (lane&3)^((lane>>3)&3).
  const u16* bptr[2];
  int boff[2];
#pragma unroll
  for (int jj = 0; jj < 2; ++jj) {
    const int j = w * 2 + jj;
    bptr[jj] = W + (size_t)(n0 + j * 16 + (lane >> 2)) * 1024 +
               ((lane & 3) ^ ((lane >> 3) & 3)) * 8;
    boff[jj] = j * 1024;
  }

// per wave per tile: 4 A-gloads + 2 B-gloads = 6 VMEM ops
#define ISSUE(T, BUF)                                            \
  do {                                                           \
    _Pragma("unroll") for (int jj = 0; jj < 4; ++jj)             \
        GLOAD16(aptr[jj] + (size_t)(T) * 32, As[BUF] + aoff[jj]); \
    _Pragma("unroll") for (int jj = 0; jj < 2; ++jj)             \
        GLOAD16(bptr[jj] + (size_t)(T) * 32, Bs[BUF] + boff[jj]); \
  } while (0)

  f32x4 acc[4][4] = {};

#define CMP(BUF)                                                              \
  do {                                                                       \
    u16x8 af[4], bfr[4];                                                     \
    _Pragma("unroll") for (int mi = 0; mi < 4; ++mi) {                        \
      const int row = wm * 64 + mi * 16 + lr;                                \
      const int rs = row & 7;                                                \
      const f32x4 c0 =                                                       \
          *(const f32x4*)(As[BUF] + row * 128 + (((lg * 2) ^ rs) * 16));     \
      const f32x4 c1 =                                                       \
          *(const f32x4*)(As[BUF] + row * 128 + (((lg * 2 + 1) ^ rs) * 16)); \
      u32x4 pk;                                                              \
      pk[0] = cvt_pk_bf16(c0[0], c0[1]);                                     \
      pk[1] = cvt_pk_bf16(c0[2], c0[3]);                                     \
      pk[2] = cvt_pk_bf16(c1[0], c1[1]);                                     \
      pk[3] = cvt_pk_bf16(c1[2], c1[3]);                                     \
      af[mi] = __builtin_bit_cast(u16x8, pk);                                \
    }                                                                         \
    _Pragma("unroll") for (int ni = 0; ni < 4; ++ni) {                        \
      const int row = wn * 64 + ni * 16 + lr;                                \
      bfr[ni] = *(const u16x8*)(Bs[BUF] + row * 64 +                         \
                                ((lg ^ ((row >> 1) & 3)) * 16));             \
    }                                                                         \
    _Pragma("unroll") for (int mi = 0; mi < 4; ++mi)                          \
        _Pragma("unroll") for (int ni = 0; ni < 4; ++ni)                      \
            acc[mi][ni] = mfma16(af[mi], bfr[ni], acc[mi][ni]);               \
  } while (0)

  // prologue: 3 tiles in flight (18 ops); drain tile 0 only
  ISSUE(0, 0);
  ISSUE(1, 1);
  ISSUE(2, 2);
  asm volatile("s_waitcnt vmcnt(12)" ::: "memory");
  BARX();

  for (int tt = 0; tt < 29; ++tt) {
    CMP(tt % 3);
    // drain my ds_reads before any wave can overwrite this buffer
    asm volatile("s_waitcnt lgkmcnt(0)" ::: "memory");
    BARX();
    ISSUE(tt + 3, tt % 3);                              // refill freed buffer
    asm volatile("s_waitcnt vmcnt(12)" ::: "memory");   // tile tt+1 landed
    BARX();
  }
  // tail: outstanding {T30,T31} = 12
  CMP(29 % 3);
  asm volatile("s_waitcnt vmcnt(6)" ::: "memory");      // T30 landed
  BARX();
  CMP(30 % 3);
  asm volatile("s_waitcnt vmcnt(0)" ::: "memory");      // T31 landed
  BARX();
  CMP(31 % 3);
#undef ISSUE
#undef CMP

  // epilogue: C row(m) = lg*4 + r, col(n) = lr
#pragma unroll
  for (int mi = 0; mi < 4; ++mi) {
    const int sbase = m0 + wm * 64 + mi * 16 + lg * 4;
    const int b_ = sbase >> 11;
    const int s_ = sbase & 2047;
#pragma unroll
    for (int ni = 0; ni < 4; ++ni) {
      const int n = n0 + wn * 64 + ni * 16 + lr;
      const int h_ = n >> 6, dh = n & 63;
      if (mode == 2) {
        u16x4 pk;
        pk[0] = f2bf(acc[mi][ni][0]);
        pk[1] = f2bf(acc[mi][ni][1]);
        pk[2] = f2bf(acc[mi][ni][2]);
        pk[3] = f2bf(acc[mi][ni][3]);
        *(u16x4*)(Vt + ((size_t)((b_ * 16 + h_) * 64 + dh)) * 2048 + s_) = pk;
      } else {
        // Q: fold 1/sqrt(64) * log2(e) so attn softmax runs in exp2 domain
        const float sc = (mode == 0) ? 0.18033688f : 1.0f;
        u16* dst = (mode == 0 ? Qb : Kb) + (size_t)(b_ * 16 + h_) * (2048 * 64) + dh;
#pragma unroll
        for (int r = 0; r < 4; ++r)
          dst[(size_t)(s_ + r) * 64] = f2bf(acc[mi][ni][r] * sc);
      }
    }
  }
}

// ---------------------------------------------------------------- attention
__global__ __launch_bounds__(256, 2) void attn_kernel(
    const u16* __restrict__ Qb, const u16* __restrict__ Kb, const u16* __restrict__ Vt,
    const int* __restrict__ pad, float* __restrict__ out) {
  // Paired q-tiles: block does qbA=31-pi (kv 0..qbA) and qbB=pi (kv 0..qbB),
  // sharing staged K/V. MFMA-steps = 33 const. Block id and id+256 land on the
  // same CU (round-robin) and get pi = p and 15-p -> loop-length sum 49 const.
  const int id = blockIdx.x;
  const int g = id >> 8, r_ = id & 255;
  const int bh = r_ & 31;
  const int p8 = r_ >> 5;
  const int pi = g ? (15 - p8) : p8;
  const int qbA = 31 - pi, qbB = pi;

  const int b = bh >> 4, h = bh & 15;
  const u16* Qh = Qb + (size_t)bh * (2048 * 64);
  const u16* Kh = Kb + (size_t)bh * (2048 * 64);
  const u16* Vh = Vt + (size_t)bh * (64 * 2048);
  const int* padb = pad + b * 2048;

  __shared__ u16 Ks[2][64 * 64];  // [kv][d], 128B rows, XOR-swizzled, dbuf
  __shared__ u16 Vs[2][64 * 64];  // [d][kv], 128B rows, XOR-swizzled, dbuf
  __shared__ u16 Ps[4][16 * 64];  // per-wave P scratch (reused by both tiles)

  const int t = threadIdx.x, lane = t & 63, w = t >> 6;
  const int lr = lane & 15, lg = lane >> 4;
  const int swz = (lr & 7) << 4;
  const int sr = t >> 3, scb = t & 7;
  const int qwaveA = qbA * 64 + w * 16, qwaveB = qbB * 64 + w * 16;

  // Q fragments for both tiles (lane = q-row lr)
  u16x8 qfA[2], qfB[2];
#pragma unroll
  for (int kc = 0; kc < 2; ++kc) {
    qfA[kc] = *(const u16x8*)(Qh + (size_t)(qwaveA + lr) * 64 + kc * 32 + lg * 8);
    qfB[kc] = *(const u16x8*)(Qh + (size_t)(qwaveB + lr) * 64 + kc * 32 + lg * 8);
  }

  f32x4 accA[4] = {}, accB[4] = {};
  float mrowA = -1e4f, lsumA = 0.f, mrowB = -1e4f, lsumB = 0.f;

  u16x8 kr0, kr1, vr0, vr1;
  const int sb0 = (sr * 128 + scb * 16) ^ ((sr & 7) << 4);
  const int sb1 = ((32 + sr) * 128 + scb * 16) ^ ((sr & 7) << 4);

  kr0 = *(const u16x8*)(Kh + (size_t)sr * 64 + scb * 8);
  kr1 = *(const u16x8*)(Kh + (size_t)(32 + sr) * 64 + scb * 8);
  vr0 = *(const u16x8*)(Vh + (size_t)sr * 2048 + scb * 8);
  vr1 = *(const u16x8*)(Vh + (size_t)(32 + sr) * 2048 + scb * 8);
  *(u16x8*)((char*)Ks[0] + sb0) = kr0;
  *(u16x8*)((char*)Ks[0] + sb1) = kr1;
  *(u16x8*)((char*)Vs[0] + sb0) = vr0;
  *(u16x8*)((char*)Vs[0] + sb1) = vr1;
  __syncthreads();

// one q-tile's QK^T + online softmax (defer-max) + PV for the current kv step
#define PROCESS(QF, ACC, MROW, LSUM, QWAVE)                                    \
  do {                                                                         \
    f32x4 s4[4] = {};                                                          \
    __builtin_amdgcn_s_setprio(1);                                             \
    _Pragma("unroll") for (int ct = 0; ct < 4; ++ct) {                         \
      if (kv0 + ct * 16 <= (QWAVE) + 15) {                                     \
        _Pragma("unroll") for (int kc = 0; kc < 2; ++kc) {                     \
          const int byt = ((ct * 16 + lr) * 128 + kc * 64 + lg * 16) ^ swz;    \
          const u16x8 kf = *(const u16x8*)((char*)KsC + byt);                  \
          s4[ct] = mfma16(kf, QF[kc], s4[ct]);                                 \
        }                                                                      \
      }                                                                        \
    }                                                                          \
    __builtin_amdgcn_s_setprio(0);                                             \
    float vv[4][4];                                                            \
    if ((kv0 + 63 <= (QWAVE)) && allpad) {                                     \
      _Pragma("unroll") for (int ct = 0; ct < 4; ++ct)                         \
          _Pragma("unroll") for (int rr = 0; rr < 4; ++rr)                     \
              vv[ct][rr] = s4[ct][rr];                                         \
    } else {                                                                   \
      const int lim = (QWAVE) + lr - kv0 - lg * 4;                             \
      _Pragma("unroll") for (int ct = 0; ct < 4; ++ct) {                       \
        const int* pvp = (const int*)&pv4[ct];                                 \
        _Pragma("unroll") for (int rr = 0; rr < 4; ++rr)                       \
            vv[ct][rr] = (pvp[rr] && (ct * 16 + rr) <= lim) ? s4[ct][rr]       \
                                                            : -1e4f;           \
      }                                                                        \
    }                                                                          \
    float m0_ = fmaxf(fmaxf(fmaxf(vv[0][0], vv[0][1]), fmaxf(vv[0][2], vv[0][3])), \
                      fmaxf(fmaxf(vv[1][0], vv[1][1]), fmaxf(vv[1][2], vv[1][3]))); \
    float m1_ = fmaxf(fmaxf(fmaxf(vv[2][0], vv[2][1]), fmaxf(vv[2][2], vv[2][3])), \
                      fmaxf(fmaxf(vv[3][0], vv[3][1]), fmaxf(vv[3][2], vv[3][3]))); \
    float mx = fmaxf(m0_, m1_);                                                \
    mx = fmaxf(mx, __shfl_xor(mx, 16));                                        \
    mx = fmaxf(mx, __shfl_xor(mx, 32));                                        \
    if (!__all(mx <= (MROW) + 8.0f)) { /* defer-max: rescale only when needed */\
      const float mn = fmaxf((MROW), mx);                                      \
      const float al = exp2f((MROW) - mn);                                     \
      (MROW) = mn;                                                             \
      (LSUM) *= al;                                                            \
      _Pragma("unroll") for (int rr = 0; rr < 4; ++rr) {                       \
        const float alv = bperm_f(lg * 4 + rr, al);                            \
        _Pragma("unroll") for (int dt = 0; dt < 4; ++dt) ACC[dt][rr] *= alv;   \
      }                                                                        \
    }                                                                          \
    float p[4][4];                                                             \
    _Pragma("unroll") for (int ct = 0; ct < 4; ++ct)                           \
        _Pragma("unroll") for (int rr = 0; rr < 4; ++rr)                       \
            p[ct][rr] = exp2f(vv[ct][rr] - (MROW));                            \
    float ps = (((p[0][0] + p[0][1]) + (p[0][2] + p[0][3])) +                  \
                ((p[1][0] + p[1][1]) + (p[1][2] + p[1][3]))) +                 \
               (((p[2][0] + p[2][1]) + (p[2][2] + p[2][3])) +                  \
                ((p[3][0] + p[3][1]) + (p[3][2] + p[3][3])));                  \
    ps += __shfl_xor(ps, 16);                                                  \
    ps += __shfl_xor(ps, 32);                                                  \
    (LSUM) += ps;                                                              \
    u16* PsB = &Ps[w][0];                                                      \
    _Pragma("unroll") for (int ct = 0; ct < 4; ++ct) {                         \
      u32x2 pw;                                                                \
      pw[0] = cvt_pk_bf16(p[ct][0], p[ct][1]);                                 \
      pw[1] = cvt_pk_bf16(p[ct][2], p[ct][3]);                                 \
      const int pb = (lr * 128 + ct * 32 + lg * 8) ^ swz;                      \
      *(u32x2*)((char*)PsB + pb) = pw;                                         \
    }                                                                          \
    const u16x8 pa0 = *(const u16x8*)((char*)PsB + ((lr * 128 + lg * 16) ^ swz));      \
    const u16x8 pa1 = *(const u16x8*)((char*)PsB + ((lr * 128 + 64 + lg * 16) ^ swz)); \
    __builtin_amdgcn_s_setprio(1);                                             \
    _Pragma("unroll") for (int dt = 0; dt < 4; ++dt) {                         \
      const int r0 = (dt * 16 + lr) * 128;                                     \
      ACC[dt] = mfma16(pa0, *(const u16x8*)((char*)VsC + ((r0 + lg * 16) ^ swz)), ACC[dt]);      \
      ACC[dt] = mfma16(pa1, *(const u16x8*)((char*)VsC + ((r0 + 64 + lg * 16) ^ swz)), ACC[dt]); \
    }                                                                          \
    __builtin_amdgcn_s_setprio(0);                                             \
  } while (0)

  int cur = 0;
  const int nst = qbA + 1;
  for (int st = 0; st < nst; ++st) {
    const int kv0 = st << 6;
    const bool more = st + 1 < nst;
    if (more) {
      const int nv0 = kv0 + 64;
      kr0 = *(const u16x8*)(Kh + (size_t)(nv0 + sr) * 64 + scb * 8);
      kr1 = *(const u16x8*)(Kh + (size_t)(nv0 + 32 + sr) * 64 + scb * 8);
      vr0 = *(const u16x8*)(Vh + (size_t)sr * 2048 + nv0 + scb * 8);
      vr1 = *(const u16x8*)(Vh + (size_t)(32 + sr) * 2048 + nv0 + scb * 8);
    }
    int4 pv4[4];
#pragma unroll
    for (int ct = 0; ct < 4; ++ct)
      pv4[ct] = *(const int4*)(padb + kv0 + ct * 16 + lg * 4);
    const int pall = pv4[0].x & pv4[0].y & pv4[0].z & pv4[0].w &
                     pv4[1].x & pv4[1].y & pv4[1].z & pv4[1].w &
                     pv4[2].x & pv4[2].y & pv4[2].z & pv4[2].w &
                     pv4[3].x & pv4[3].y & pv4[3].z & pv4[3].w;
    const bool allpad = __all(pall != 0);

    const u16* KsC = Ks[cur];
    const u16* VsC = Vs[cur];

    PROCESS(qfA, accA, mrowA, lsumA, qwaveA);       // hi tile: active all steps
    if (st <= qbB)
      PROCESS(qfB, accB, mrowB, lsumB, qwaveB);     // lo tile: shares K/V stage

    if (more) {
      u16* Kn = Ks[cur ^ 1];
      u16* Vn = Vs[cur ^ 1];
      *(u16x8*)((char*)Kn + sb0) = kr0;
      *(u16x8*)((char*)Kn + sb1) = kr1;
      *(u16x8*)((char*)Vn + sb0) = vr0;
      *(u16x8*)((char*)Vn + sb1) = vr1;
    }
    __syncthreads();
    cur ^= 1;
  }
#undef PROCESS

  // epilogue: out[b][q][h*64+d] = acc/l for both tiles
#pragma unroll
  for (int tile = 0; tile < 2; ++tile) {
    const f32x4* acc = tile ? accB : accA;
    const float lsum = tile ? lsumB : lsumA;
    const int qwave = tile ? qwaveB : qwaveA;
    const float il = 1.0f / lsum;
    float* obase = out + ((size_t)(b * 2048 + qwave + lg * 4)) * 1024 + h * 64 + lr;
#pragma unroll
    for (int r = 0; r < 4; ++r) {
      const float linv = bperm_f(lg * 4 + r, il);
#pragma unroll
      for (int dt = 0; dt < 4; ++dt)
        obase[(size_t)r * 1024 + dt * 16] = acc[dt][r] * linv;
    }
  }
}

extern "C" void kernel_launch(void* const* d_in, const int* in_sizes, int n_in,
                              void* d_out, int out_size, void* d_ws, size_t ws_size,
                              hipStream_t stream) {
  const float* q  = (const float*)d_in[0];
  const float* k  = (const float*)d_in[1];
  const float* v  = (const float*)d_in[2];
  const float* wq = (const float*)d_in[3];
  const float* wk = (const float*)d_in[4];
  const float* wv = (const float*)d_in[5];
  const int* pad  = (const int*)d_in[6];
  float* out = (float*)d_out;

  u16* Qb  = (u16*)d_ws;                    // [B,H,S,64] bf16, pre-scaled (8MB)
  u16* Kb  = Qb + (size_t)4 * 1024 * 1024;  // [B,H,S,64] bf16 (8MB)
  u16* Vt  = Kb + (size_t)4 * 1024 * 1024;  // [B,H,64,S] bf16 (8MB)
  u16* Wbf = Vt + (size_t)4 * 1024 * 1024;  // [3][1024][1024] bf16 (6MB)

  dim3 gc(512, 3);
  wconv_kernel<<<gc, 256, 0, stream>>>(wq, wk, wv, Wbf);

  proj_kernel<<<768, 256, 0, stream>>>(q, k, v, Wbf, Qb, Kb, Vt);

  attn_kernel<<<512, 256, 0, stream>>>(Qb, Kb, Vt, pad, out);
}

// Round 11
// 105.961 us; speedup vs baseline: 1.0405x; 1.0405x over previous
//
#include <hip/hip_runtime.h>

// MHA: B=2, S=2048, D=1024, H=16, DH=64. f32 in/out, bf16 MFMA internally.
// cvt_kernel:  Xq/Xk/Xv and Wq/Wk/Wv f32 -> bf16 (one pass; X read once, W read
//              16x by gemm -> convert both once).
// proj_kernel: fused Q/K/V = Xbf @ Wbf^T (768 blocks, 128x128, BK=32). Pure-bf16:
//              BOTH operands staged via global_load_lds (linear source, linear
//              LDS, round-8-proven 0-conflict read pattern). 3-buffer ring,
//              depth-3 prefetch, counted vmcnt (8/4/0), lgkmcnt(0) before the
//              overwrite barrier. No staging registers -> compile-deterministic.
// attn_kernel: paired q-tiles flash attention (unchanged from round 8).

typedef unsigned short u16;
typedef unsigned int u32;
typedef u16 u16x4 __attribute__((ext_vector_type(4)));
typedef u16 u16x8 __attribute__((ext_vector_type(8)));
typedef u32 u32x2 __attribute__((ext_vector_type(2)));
typedef u32 u32x4 __attribute__((ext_vector_type(4)));
typedef __bf16 bf16x8 __attribute__((ext_vector_type(8)));
typedef float f32x4 __attribute__((ext_vector_type(4)));

static __device__ __forceinline__ u16 f2bf(float f) {
  unsigned u = __builtin_bit_cast(unsigned, f);
  return (u16)((u + 0x7FFFu + ((u >> 16) & 1u)) >> 16);
}

static __device__ __forceinline__ u32 cvt_pk_bf16(float lo, float hi) {
  u32 r;
  asm("v_cvt_pk_bf16_f32 %0, %1, %2" : "=v"(r) : "v"(lo), "v"(hi));
  return r;
}

static __device__ __forceinline__ u16x8 cvt8(float4 f0, float4 f1) {
  u32x4 v;
  v[0] = cvt_pk_bf16(f0.x, f0.y);
  v[1] = cvt_pk_bf16(f0.z, f0.w);
  v[2] = cvt_pk_bf16(f1.x, f1.y);
  v[3] = cvt_pk_bf16(f1.z, f1.w);
  return __builtin_bit_cast(u16x8, v);
}

static __device__ __forceinline__ f32x4 mfma16(u16x8 a, u16x8 b, f32x4 c) {
  return __builtin_amdgcn_mfma_f32_16x16x32_bf16(
      __builtin_bit_cast(bf16x8, a), __builtin_bit_cast(bf16x8, b), c, 0, 0, 0);
}

static __device__ __forceinline__ float bperm_f(int lane, float v) {
  return __builtin_bit_cast(
      float, __builtin_amdgcn_ds_bpermute(lane * 4, __builtin_bit_cast(int, v)));
}

// async global->LDS, 16B/lane; LDS dest = wave-uniform base (+ lane*16 by HW)
#define GLOAD16(GSRC, LDST)                                                  \
  __builtin_amdgcn_global_load_lds(                                         \
      (const __attribute__((address_space(1))) unsigned int*)(GSRC),        \
      (__attribute__((address_space(3))) unsigned int*)(LDST), 16, 0, 0)

#define FENCE() asm volatile("" ::: "memory")
#define BARX()                        \
  do {                                \
    __builtin_amdgcn_s_barrier();     \
    FENCE();                          \
  } while (0)

// ---------------------------------------------------------------- f32 -> bf16
__global__ __launch_bounds__(256) void cvt_kernel(
    const float* __restrict__ Xq, const float* __restrict__ Xk,
    const float* __restrict__ Xv, const float* __restrict__ Wq,
    const float* __restrict__ Wk, const float* __restrict__ Wv,
    u16* __restrict__ Xb, u16* __restrict__ Wb) {
  const int y = blockIdx.y;
  const float* src = (y == 0) ? Xq : (y == 1) ? Xk : (y == 2) ? Xv
                   : (y == 3) ? Wq : (y == 4) ? Wk : Wv;
  const size_t nelem = (y < 3) ? (size_t)4 * 1024 * 1024 : (size_t)1024 * 1024;
  u16* dst = (y < 3) ? Xb + (size_t)y * 4 * 1024 * 1024
                     : Wb + (size_t)(y - 3) * 1024 * 1024;
  const size_t i = ((size_t)blockIdx.x * 256 + threadIdx.x) * 8;
  if (i >= nelem) return;
  const float4 f0 = *(const float4*)(src + i);
  const float4 f1 = *(const float4*)(src + i + 4);
  *(u16x8*)(dst + i) = cvt8(f0, f1);
}

// ---------------------------------------------------------------- projections
__global__ __launch_bounds__(256) void proj_kernel(
    const u16* __restrict__ Xbf, const u16* __restrict__ Wbf,
    u16* __restrict__ Qb, u16* __restrict__ Kb, u16* __restrict__ Vt) {
  // XCD-chunk remap (768 = 8*96, bijective); n fastest within a chunk so the
  // 8 n-blocks sharing an X m-slice run consecutively on one XCD.
  const int d0 = blockIdx.x;
  const int tid = (d0 & 7) * 96 + (d0 >> 3);
  const int nI = tid % 24, mI = tid / 24;
  const int mode = nI >> 3;        // 0=Q 1=K 2=V
  const int m0 = mI * 128;
  const int n0 = (nI & 7) * 128;

  const u16* __restrict__ X = Xbf + (size_t)mode * (4 * 1024 * 1024);
  const u16* __restrict__ W = Wbf + (size_t)mode * (1024 * 1024);

  // bf16 [128 rows][32 k] per tile = 8KB; rows at 64B pitch, fully linear.
  // Read pattern row*64 + lg*16 measured 0 bank conflicts (round 8).
  __shared__ __align__(16) char As[3][128 * 64];
  __shared__ __align__(16) char Bs[3][128 * 64];

  const int t = threadIdx.x;
  const int lane = t & 63;
  const int w = t >> 6;
  const int wm = w >> 1, wn = w & 1;
  const int lr = lane & 15, lg = lane >> 4;

  // staging: 8 instrs of 1KB per matrix (16 rows x 4 slots); 2 per wave each.
  // instr j: lane -> row j*16 + (lane>>2), 16B slot lane&3. Linear both sides.
  const u16* aptr[2];
  const u16* bptr[2];
  int soff[2];
#pragma unroll
  for (int jj = 0; jj < 2; ++jj) {
    const int j = w * 2 + jj;
    const int row = j * 16 + (lane >> 2);
    const int col = (lane & 3) * 8;
    aptr[jj] = X + (size_t)(m0 + row) * 1024 + col;
    bptr[jj] = W + (size_t)(n0 + row) * 1024 + col;
    soff[jj] = j * 1024;
  }

// per wave per tile: 2 A + 2 B = 4 VMEM ops
#define ISSUE(T, BUF)                                                \
  do {                                                               \
    _Pragma("unroll") for (int jj = 0; jj < 2; ++jj)                 \
        GLOAD16(aptr[jj] + (size_t)(T) * 32, As[BUF] + soff[jj]);    \
    _Pragma("unroll") for (int jj = 0; jj < 2; ++jj)                 \
        GLOAD16(bptr[jj] + (size_t)(T) * 32, Bs[BUF] + soff[jj]);    \
  } while (0)

  f32x4 acc[4][4] = {};

#define CMP(BUF)                                                              \
  do {                                                                       \
    u16x8 af[4], bfr[4];                                                     \
    _Pragma("unroll") for (int mi = 0; mi < 4; ++mi) {                        \
      const int row = wm * 64 + mi * 16 + lr;                                \
      af[mi] = *(const u16x8*)(As[BUF] + row * 64 + lg * 16);                \
    }                                                                         \
    _Pragma("unroll") for (int ni = 0; ni < 4; ++ni) {                        \
      const int row = wn * 64 + ni * 16 + lr;                                \
      bfr[ni] = *(const u16x8*)(Bs[BUF] + row * 64 + lg * 16);               \
    }                                                                         \
    _Pragma("unroll") for (int mi = 0; mi < 4; ++mi)                          \
        _Pragma("unroll") for (int ni = 0; ni < 4; ++ni)                      \
            acc[mi][ni] = mfma16(af[mi], bfr[ni], acc[mi][ni]);               \
  } while (0)

  // prologue: 3 tiles in flight (12 ops); drain tile 0 only
  ISSUE(0, 0);
  ISSUE(1, 1);
  ISSUE(2, 2);
  asm volatile("s_waitcnt vmcnt(8)" ::: "memory");
  BARX();

  for (int tt = 0; tt < 29; ++tt) {
    CMP(tt % 3);
    // my ds_reads must be serviced before any wave overwrites this buffer
    asm volatile("s_waitcnt lgkmcnt(0)" ::: "memory");
    BARX();
    ISSUE(tt + 3, tt % 3);                             // refill freed buffer
    asm volatile("s_waitcnt vmcnt(8)" ::: "memory");   // tile tt+1 landed
    BARX();
  }
  // tail: outstanding {T30,T31} = 8
  CMP(29 % 3);
  asm volatile("s_waitcnt vmcnt(4)" ::: "memory");     // T30 landed
  BARX();
  CMP(30 % 3);
  asm volatile("s_waitcnt vmcnt(0)" ::: "memory");     // T31 landed
  BARX();
  CMP(31 % 3);
#undef ISSUE
#undef CMP

  // epilogue: C row(m) = lg*4 + r, col(n) = lr
#pragma unroll
  for (int mi = 0; mi < 4; ++mi) {
    const int sbase = m0 + wm * 64 + mi * 16 + lg * 4;
    const int b_ = sbase >> 11;
    const int s_ = sbase & 2047;
#pragma unroll
    for (int ni = 0; ni < 4; ++ni) {
      const int n = n0 + wn * 64 + ni * 16 + lr;
      const int h_ = n >> 6, dh = n & 63;
      if (mode == 2) {
        u16x4 pk;
        pk[0] = f2bf(acc[mi][ni][0]);
        pk[1] = f2bf(acc[mi][ni][1]);
        pk[2] = f2bf(acc[mi][ni][2]);
        pk[3] = f2bf(acc[mi][ni][3]);
        *(u16x4*)(Vt + ((size_t)((b_ * 16 + h_) * 64 + dh)) * 2048 + s_) = pk;
      } else {
        // Q: fold 1/sqrt(64) * log2(e) so attn softmax runs in exp2 domain
        const float sc = (mode == 0) ? 0.18033688f : 1.0f;
        u16* dst = (mode == 0 ? Qb : Kb) + (size_t)(b_ * 16 + h_) * (2048 * 64) + dh;
#pragma unroll
        for (int r = 0; r < 4; ++r)
          dst[(size_t)(s_ + r) * 64] = f2bf(acc[mi][ni][r] * sc);
      }
    }
  }
}

// ---------------------------------------------------------------- attention
__global__ __launch_bounds__(256, 2) void attn_kernel(
    const u16* __restrict__ Qb, const u16* __restrict__ Kb, const u16* __restrict__ Vt,
    const int* __restrict__ pad, float* __restrict__ out) {
  // Paired q-tiles: block does qbA=31-pi (kv 0..qbA) and qbB=pi (kv 0..qbB),
  // sharing staged K/V. MFMA-steps = 33 const. Block id and id+256 land on the
  // same CU (round-robin) and get pi = p and 15-p -> loop-length sum 49 const.
  const int id = blockIdx.x;
  const int g = id >> 8, r_ = id & 255;
  const int bh = r_ & 31;
  const int p8 = r_ >> 5;
  const int pi = g ? (15 - p8) : p8;
  const int qbA = 31 - pi, qbB = pi;

  const int b = bh >> 4, h = bh & 15;
  const u16* Qh = Qb + (size_t)bh * (2048 * 64);
  const u16* Kh = Kb + (size_t)bh * (2048 * 64);
  const u16* Vh = Vt + (size_t)bh * (64 * 2048);
  const int* padb = pad + b * 2048;

  __shared__ u16 Ks[2][64 * 64];  // [kv][d], 128B rows, XOR-swizzled, dbuf
  __shared__ u16 Vs[2][64 * 64];  // [d][kv], 128B rows, XOR-swizzled, dbuf
  __shared__ u16 Ps[4][16 * 64];  // per-wave P scratch (reused by both tiles)

  const int t = threadIdx.x, lane = t & 63, w = t >> 6;
  const int lr = lane & 15, lg = lane >> 4;
  const int swz = (lr & 7) << 4;
  const int sr = t >> 3, scb = t & 7;
  const int qwaveA = qbA * 64 + w * 16, qwaveB = qbB * 64 + w * 16;

  // Q fragments for both tiles (lane = q-row lr)
  u16x8 qfA[2], qfB[2];
#pragma unroll
  for (int kc = 0; kc < 2; ++kc) {
    qfA[kc] = *(const u16x8*)(Qh + (size_t)(qwaveA + lr) * 64 + kc * 32 + lg * 8);
    qfB[kc] = *(const u16x8*)(Qh + (size_t)(qwaveB + lr) * 64 + kc * 32 + lg * 8);
  }

  f32x4 accA[4] = {}, accB[4] = {};
  float mrowA = -1e4f, lsumA = 0.f, mrowB = -1e4f, lsumB = 0.f;

  u16x8 kr0, kr1, vr0, vr1;
  const int sb0 = (sr * 128 + scb * 16) ^ ((sr & 7) << 4);
  const int sb1 = ((32 + sr) * 128 + scb * 16) ^ ((sr & 7) << 4);

  kr0 = *(const u16x8*)(Kh + (size_t)sr * 64 + scb * 8);
  kr1 = *(const u16x8*)(Kh + (size_t)(32 + sr) * 64 + scb * 8);
  vr0 = *(const u16x8*)(Vh + (size_t)sr * 2048 + scb * 8);
  vr1 = *(const u16x8*)(Vh + (size_t)(32 + sr) * 2048 + scb * 8);
  *(u16x8*)((char*)Ks[0] + sb0) = kr0;
  *(u16x8*)((char*)Ks[0] + sb1) = kr1;
  *(u16x8*)((char*)Vs[0] + sb0) = vr0;
  *(u16x8*)((char*)Vs[0] + sb1) = vr1;
  __syncthreads();

// one q-tile's QK^T + online softmax (defer-max) + PV for the current kv step
#define PROCESS(QF, ACC, MROW, LSUM, QWAVE)                                    \
  do {                                                                         \
    f32x4 s4[4] = {};                                                          \
    __builtin_amdgcn_s_setprio(1);                                             \
    _Pragma("unroll") for (int ct = 0; ct < 4; ++ct) {                         \
      if (kv0 + ct * 16 <= (QWAVE) + 15) {                                     \
        _Pragma("unroll") for (int kc = 0; kc < 2; ++kc) {                     \
          const int byt = ((ct * 16 + lr) * 128 + kc * 64 + lg * 16) ^ swz;    \
          const u16x8 kf = *(const u16x8*)((char*)KsC + byt);                  \
          s4[ct] = mfma16(kf, QF[kc], s4[ct]);                                 \
        }                                                                      \
      }                                                                        \
    }                                                                          \
    __builtin_amdgcn_s_setprio(0);                                             \
    float vv[4][4];                                                            \
    if ((kv0 + 63 <= (QWAVE)) && allpad) {                                     \
      _Pragma("unroll") for (int ct = 0; ct < 4; ++ct)                         \
          _Pragma("unroll") for (int rr = 0; rr < 4; ++rr)                     \
              vv[ct][rr] = s4[ct][rr];                                         \
    } else {                                                                   \
      const int lim = (QWAVE) + lr - kv0 - lg * 4;                             \
      _Pragma("unroll") for (int ct = 0; ct < 4; ++ct) {                       \
        const int* pvp = (const int*)&pv4[ct];                                 \
        _Pragma("unroll") for (int rr = 0; rr < 4; ++rr)                       \
            vv[ct][rr] = (pvp[rr] && (ct * 16 + rr) <= lim) ? s4[ct][rr]       \
                                                            : -1e4f;           \
      }                                                                        \
    }                                                                          \
    float m0_ = fmaxf(fmaxf(fmaxf(vv[0][0], vv[0][1]), fmaxf(vv[0][2], vv[0][3])), \
                      fmaxf(fmaxf(vv[1][0], vv[1][1]), fmaxf(vv[1][2], vv[1][3]))); \
    float m1_ = fmaxf(fmaxf(fmaxf(vv[2][0], vv[2][1]), fmaxf(vv[2][2], vv[2][3])), \
                      fmaxf(fmaxf(vv[3][0], vv[3][1]), fmaxf(vv[3][2], vv[3][3]))); \
    float mx = fmaxf(m0_, m1_);                                                \
    mx = fmaxf(mx, __shfl_xor(mx, 16));                                        \
    mx = fmaxf(mx, __shfl_xor(mx, 32));                                        \
    if (!__all(mx <= (MROW) + 8.0f)) { /* defer-max: rescale only when needed */\
      const float mn = fmaxf((MROW), mx);                                      \
      const float al = exp2f((MROW) - mn);                                     \
      (MROW) = mn;                                                             \
      (LSUM) *= al;                                                            \
      _Pragma("unroll") for (int rr = 0; rr < 4; ++rr) {                       \
        const float alv = bperm_f(lg * 4 + rr, al);                            \
        _Pragma("unroll") for (int dt = 0; dt < 4; ++dt) ACC[dt][rr] *= alv;   \
      }                                                                        \
    }                                                                          \
    float p[4][4];                                                             \
    _Pragma("unroll") for (int ct = 0; ct < 4; ++ct)                           \
        _Pragma("unroll") for (int rr = 0; rr < 4; ++rr)                       \
            p[ct][rr] = exp2f(vv[ct][rr] - (MROW));                            \
    float ps = (((p[0][0] + p[0][1]) + (p[0][2] + p[0][3])) +                  \
                ((p[1][0] + p[1][1]) + (p[1][2] + p[1][3]))) +                 \
               (((p[2][0] + p[2][1]) + (p[2][2] + p[2][3])) +                  \
                ((p[3][0] + p[3][1]) + (p[3][2] + p[3][3])));                  \
    ps += __shfl_xor(ps, 16);                                                  \
    ps += __shfl_xor(ps, 32);                                                  \
    (LSUM) += ps;                                                              \
    u16* PsB = &Ps[w][0];                                                      \
    _Pragma("unroll") for (int ct = 0; ct < 4; ++ct) {                         \
      u32x2 pw;                                                                \
      pw[0] = cvt_pk_bf16(p[ct][0], p[ct][1]);                                 \
      pw[1] = cvt_pk_bf16(p[ct][2], p[ct][3]);                                 \
      const int pb = (lr * 128 + ct * 32 + lg * 8) ^ swz;                      \
      *(u32x2*)((char*)PsB + pb) = pw;                                         \
    }                                                                          \
    const u16x8 pa0 = *(const u16x8*)((char*)PsB + ((lr * 128 + lg * 16) ^ swz));      \
    const u16x8 pa1 = *(const u16x8*)((char*)PsB + ((lr * 128 + 64 + lg * 16) ^ swz)); \
    __builtin_amdgcn_s_setprio(1);                                             \
    _Pragma("unroll") for (int dt = 0; dt < 4; ++dt) {                         \
      const int r0 = (dt * 16 + lr) * 128;                                     \
      ACC[dt] = mfma16(pa0, *(const u16x8*)((char*)VsC + ((r0 + lg * 16) ^ swz)), ACC[dt]);      \
      ACC[dt] = mfma16(pa1, *(const u16x8*)((char*)VsC + ((r0 + 64 + lg * 16) ^ swz)), ACC[dt]); \
    }                                                                          \
    __builtin_amdgcn_s_setprio(0);                                             \
  } while (0)

  int cur = 0;
  const int nst = qbA + 1;
  for (int st = 0; st < nst; ++st) {
    const int kv0 = st << 6;
    const bool more = st + 1 < nst;
    if (more) {
      const int nv0 = kv0 + 64;
      kr0 = *(const u16x8*)(Kh + (size_t)(nv0 + sr) * 64 + scb * 8);
      kr1 = *(const u16x8*)(Kh + (size_t)(nv0 + 32 + sr) * 64 + scb * 8);
      vr0 = *(const u16x8*)(Vh + (size_t)sr * 2048 + nv0 + scb * 8);
      vr1 = *(const u16x8*)(Vh + (size_t)(32 + sr) * 2048 + nv0 + scb * 8);
    }
    int4 pv4[4];
#pragma unroll
    for (int ct = 0; ct < 4; ++ct)
      pv4[ct] = *(const int4*)(padb + kv0 + ct * 16 + lg * 4);
    const int pall = pv4[0].x & pv4[0].y & pv4[0].z & pv4[0].w &
                     pv4[1].x & pv4[1].y & pv4[1].z & pv4[1].w &
                     pv4[2].x & pv4[2].y & pv4[2].z & pv4[2].w &
                     pv4[3].x & pv4[3].y & pv4[3].z & pv4[3].w;
    const bool allpad = __all(pall != 0);

    const u16* KsC = Ks[cur];
    const u16* VsC = Vs[cur];

    PROCESS(qfA, accA, mrowA, lsumA, qwaveA);       // hi tile: active all steps
    if (st <= qbB)
      PROCESS(qfB, accB, mrowB, lsumB, qwaveB);     // lo tile: shares K/V stage

    if (more) {
      u16* Kn = Ks[cur ^ 1];
      u16* Vn = Vs[cur ^ 1];
      *(u16x8*)((char*)Kn + sb0) = kr0;
      *(u16x8*)((char*)Kn + sb1) = kr1;
      *(u16x8*)((char*)Vn + sb0) = vr0;
      *(u16x8*)((char*)Vn + sb1) = vr1;
    }
    __syncthreads();
    cur ^= 1;
  }
#undef PROCESS

  // epilogue: out[b][q][h*64+d] = acc/l for both tiles
#pragma unroll
  for (int tile = 0; tile < 2; ++tile) {
    const f32x4* acc = tile ? accB : accA;
    const float lsum = tile ? lsumB : lsumA;
    const int qwave = tile ? qwaveB : qwaveA;
    const float il = 1.0f / lsum;
    float* obase = out + ((size_t)(b * 2048 + qwave + lg * 4)) * 1024 + h * 64 + lr;
#pragma unroll
    for (int r = 0; r < 4; ++r) {
      const float linv = bperm_f(lg * 4 + r, il);
#pragma unroll
      for (int dt = 0; dt < 4; ++dt)
        obase[(size_t)r * 1024 + dt * 16] = acc[dt][r] * linv;
    }
  }
}

extern "C" void kernel_launch(void* const* d_in, const int* in_sizes, int n_in,
                              void* d_out, int out_size, void* d_ws, size_t ws_size,
                              hipStream_t stream) {
  const float* q  = (const float*)d_in[0];
  const float* k  = (const float*)d_in[1];
  const float* v  = (const float*)d_in[2];
  const float* wq = (const float*)d_in[3];
  const float* wk = (const float*)d_in[4];
  const float* wv = (const float*)d_in[5];
  const int* pad  = (const int*)d_in[6];
  float* out = (float*)d_out;

  u16* Qb  = (u16*)d_ws;                     // [B,H,S,64] bf16, pre-scaled (8MB)
  u16* Kb  = Qb + (size_t)4 * 1024 * 1024;   // [B,H,S,64] bf16 (8MB)
  u16* Vt  = Kb + (size_t)4 * 1024 * 1024;   // [B,H,64,S] bf16 (8MB)
  u16* Wbf = Vt + (size_t)4 * 1024 * 1024;   // [3][1024][1024] bf16 (6MB)
  u16* Xbf = Wbf + (size_t)3 * 1024 * 1024;  // [3][B*S][1024] bf16 (24MB)

  dim3 gv(2048, 6);  // y<3: X (4M elems), y>=3: W (1M elems; extra blocks exit)
  cvt_kernel<<<gv, 256, 0, stream>>>(q, k, v, wq, wk, wv, Xbf, Wbf);

  proj_kernel<<<768, 256, 0, stream>>>(Xbf, Wbf, Qb, Kb, Vt);

  attn_kernel<<<512, 256, 0, stream>>>(Qb, Kb, Vt, pad, out);
}